// Round 12
// baseline (104940.393 us; speedup 1.0000x reference)
//
#include <hip/hip_runtime.h>
#include <hip/hip_fp16.h>
#include <hip/hip_cooperative_groups.h>

namespace cg = cooperative_groups;

constexpr int B_ = 128, T_ = 1024, D_ = 512, U_ = 512;
constexpr int NBLK = 256, NTHR = 1024;
constexpr int G4 = 4 * U_;   // 2048 gate columns

__device__ __forceinline__ float sigm(float v) { return 1.0f / (1.0f + expf(-v)); }

#define AGENT_LD(p)    __hip_atomic_load((p), __ATOMIC_RELAXED, __HIP_MEMORY_SCOPE_AGENT)
#define AGENT_LDA(p)   __hip_atomic_load((p), __ATOMIC_ACQUIRE, __HIP_MEMORY_SCOPE_AGENT)
#define AGENT_ST(p, v) __hip_atomic_store((p), (v), __ATOMIC_RELAXED, __HIP_MEMORY_SCOPE_AGENT)

template <typename ZT> __device__ __forceinline__ ZT    to_zt(float v);
template <> __device__ __forceinline__ float  to_zt<float>(float v)  { return v; }
template <> __device__ __forceinline__ __half to_zt<__half>(float v) { return __float2half(v); }
__device__ __forceinline__ float from_zt(float v)  { return v; }
__device__ __forceinline__ float from_zt(__half v) { return __half2float(v); }

__device__ __forceinline__ float bcast_lane(float v, int lane) {
    return __int_as_float(__builtin_amdgcn_readlane(__float_as_int(v), lane));
}

// ---------------- x[b][t][k] -> xT[t][k][b] ----------------------------------------
__global__ __launch_bounds__(256) void transpose_x(const float* __restrict__ x,
                                                   float* __restrict__ xT)
{
    __shared__ float tile[32][33];
    const int tileId = blockIdx.x;
    const int bt = tileId & 3;
    const int kt = (tileId >> 2) & 15;
    const int t  = tileId >> 6;
    const int tx = threadIdx.x & 31;
    const int ty = threadIdx.x >> 5;
    #pragma unroll
    for (int r = 0; r < 4; ++r) {
        const int b = bt * 32 + ty + r * 8;
        const int k = kt * 32 + tx;
        tile[ty + r * 8][tx] = x[(size_t)b * (T_ * D_) + (size_t)t * D_ + k];
    }
    __syncthreads();
    #pragma unroll
    for (int r = 0; r < 4; ++r) {
        const int k = kt * 32 + ty + r * 8;
        const int b = bt * 32 + tx;
        xT[((size_t)t * D_ + k) * B_ + b] = tile[tx][ty + r * 8];
    }
}

// ---------------- pack W for zx_gemm: Wpk[blk256][k1024][c8] -----------------------
__global__ __launch_bounds__(1024) void pack_w(const float* __restrict__ wk,
                                               const float* __restrict__ wr,
                                               float* __restrict__ Wpk)
{
    const size_t idx = (size_t)blockIdx.x * 1024 + threadIdx.x;
    const int    c   = (int)(idx & 7);
    const size_t k   = (idx >> 3) & 1023;
    const int    blk = (int)(idx >> 13);
    const int    col = ((c >> 1) << 9) + blk * 2 + (c & 1);
    Wpk[idx] = (k < 512) ? wk[k * G4 + col] : wr[(k - 512) * G4 + col];
}

// ---------------- pack W_r: Wp3[cu32][k512][c64], col = (c>>4)*512 + cu*16 + (c&15)
__global__ __launch_bounds__(1024) void pack_w3(const float* __restrict__ wr,
                                                float* __restrict__ Wp3)
{
    const size_t idx = (size_t)blockIdx.x * 1024 + threadIdx.x;  // 1,048,576
    const int c  = (int)(idx & 63);
    const int k  = (int)((idx >> 6) & 511);
    const int cu = (int)(idx >> 15);
    const int col = ((c >> 4) << 9) + cu * 16 + (c & 15);
    Wp3[idx] = wr[(size_t)k * G4 + col];
}

// ---------------- zx[t][gc][b] = bias + x_t @ Wk  (R3-proven CHUNKED loop) ---------
template <typename ZT>
__global__ __launch_bounds__(NTHR, 4) void zx_gemm(
    const float* __restrict__ xT, const float* __restrict__ Wpk,
    const float* __restrict__ bias, ZT* __restrict__ zx)
{
    __shared__ float parts[8][128][9];
    __shared__ float bias_l[8];
    const int tid = threadIdx.x, blk = blockIdx.x, u0 = blk * 2;
    if (tid < 8) bias_l[tid] = bias[(tid >> 1) * U_ + u0 + (tid & 1)];
    const int b = tid & 127, ksub = tid >> 7;
    const int ksub_u = __builtin_amdgcn_readfirstlane(ksub);
    const float* __restrict__ wp = Wpk + ((size_t)blk * 1024 + (size_t)ksub_u * 64) * 8;
    __syncthreads();

    for (int t = 0; t < T_; ++t) {
        const float* __restrict__ xp = xT + ((size_t)t * D_ + ksub * 64) * B_ + b;
        float acc[8] = {0.f,0.f,0.f,0.f,0.f,0.f,0.f,0.f};
        #pragma unroll 2
        for (int kq = 0; kq < 16; ++kq) {
            const float v0 = xp[(kq * 4 + 0) * B_];
            const float v1 = xp[(kq * 4 + 1) * B_];
            const float v2 = xp[(kq * 4 + 2) * B_];
            const float v3 = xp[(kq * 4 + 3) * B_];
            const float* __restrict__ w = wp + kq * 32;            // wave-uniform -> s_load
            #pragma unroll
            for (int c = 0; c < 8; ++c)
                acc[c] += v0 * w[c] + v1 * w[8 + c] + v2 * w[16 + c] + v3 * w[24 + c];
        }
        #pragma unroll
        for (int c = 0; c < 8; ++c) parts[ksub][b][c] = acc[c];
        __syncthreads();
        {
            const int c = tid >> 7, bb = tid & 127;
            float s = bias_l[c];
            #pragma unroll
            for (int ks = 0; ks < 8; ++ks) s += parts[ks][bb][c];
            zx[((size_t)t * G4 + (c >> 1) * U_ + u0 + (c & 1)) * B_ + bb] = to_zt<ZT>(s);
        }
        __syncthreads();
    }
}

// ---------------- main loop v7: TWO independent chains per block -------------------
// 256 blocks x 1024 threads (proven launch shape). Chain ch = tid>>9 (512 thr,
// 8 waves). Chain group g = ch*8 + (blk&7)  -> co-resident chains serve DIFFERENT
// groups; 16 groups x 32 chains; group traffic XCD-local under round-robin.
// Chain owns rows g*8..g*8+7 and (cu = blk>>3) 16 u = 64 gate cols.
// Chain-local sync = LDS monotonic barriers (8 wave-arrivals). Group sync =
// agent ctr, 2 release-arrivals per chain (the storing waves), 1 poll lane,
// LDS go-flag fan-out. W in VGPRs; h via coalesced agent loads + readlane.
// hb [g16][p2][u512][r8]; pd [g16][p2][256]; ctrl[g*16].
template <typename ZT>
__global__ __launch_bounds__(NTHR, 4) void skiplstm_loop7(
    const ZT* __restrict__ zx, const float* __restrict__ Wp,
    const float* __restrict__ dk, const float* __restrict__ dbp,
    float* __restrict__ out, float* __restrict__ hb,
    float* __restrict__ pd, unsigned* __restrict__ ctrl)
{
    __shared__ float parts[2][8][64][9];     // 36.9 KB
    __shared__ float pdl[2][16][9];
    __shared__ float ut_l[2][8], ug_l[2][8];
    __shared__ float dk1_l[2][16], dk2_l[2][16];
    __shared__ float db_l;
    __shared__ unsigned cbar1[2], cbar2[2], go_l[2];

    const int tid = threadIdx.x;
    const int blk = blockIdx.x;
    const int ch  = tid >> 9;            // chain 0/1
    const int tc  = tid & 511;           // thread-in-chain
    const int g   = ch * 8 + (blk & 7);  // 16 groups
    const int cu  = blk >> 3;            // 0..31
    const int u0  = cu * 16;

    float*    __restrict__ hbg  = hb + (size_t)g * (2 * 512 * 8);
    float*    __restrict__ pdg  = pd + (size_t)g * (2 * 256);
    unsigned* __restrict__ gctr = ctrl + g * 16;

    if (tid < 2) { cbar1[tid] = 0; cbar2[tid] = 0; go_l[tid] = 0; }
    if (tid == 0) db_l = dbp[0];
    if (tc < 8)  { ut_l[ch][tc] = 1.f; ug_l[ch][tc] = 1.f; }
    if (tc < 16) { dk1_l[ch][tc] = dk[u0 + tc]; dk2_l[ch][tc] = dk[U_ + u0 + tc]; }

    const int guu = tc >> 3;   // (tc<128) unit 0..15
    const int gr  = tc & 7;    // row 0..7
    float c_st = 0.f, h_st = 0.f;

    const int ksI  = tc >> 6;  // wave-in-chain 0..7
    const int cI   = tc & 63;
    const int ks_u = __builtin_amdgcn_readfirstlane(ksI);
    float w_reg[64];
    {
        const float* __restrict__ wsrc = Wp + ((size_t)cu * 512 + (size_t)ks_u * 64) * 64 + cI;
        #pragma unroll
        for (int kk = 0; kk < 64; ++kk) w_reg[kk] = wsrc[kk * 64];
    }
    __syncthreads();

    #pragma unroll 1
    for (int t = 0; t < T_; ++t) {
        // ---- P0: zx prefetch (gate threads) + coalesced h slice load (all waves) ----
        float zpre[4];
        if (tc < 128) {
            const ZT* __restrict__ zb =
                zx + ((size_t)t * G4 + u0 + guu) * B_ + g * 8 + gr;
            #pragma unroll
            for (int gg = 0; gg < 4; ++gg)
                zpre[gg] = from_zt(zb[(size_t)gg * 512 * B_]);
        }
        float h_reg[8];
        {
            const float* __restrict__ hsrc = hbg + ((t + 1) & 1) * 4096 + ks_u * 512;
            #pragma unroll
            for (int j = 0; j < 8; ++j)
                h_reg[j] = AGENT_LD(hsrc + j * 64 + cI);
        }

        // ---- P1a: resolve delta(t-1) -> ug(t)  (chain wave0, lanes 0-7) ----
        if (t > 0 && tc < 8) {
            const float* __restrict__ pdt = pdg + ((t - 1) & 1) * 256;
            float s = 0.f;
            #pragma unroll
            for (int c2 = 0; c2 < 32; ++c2) s += AGENT_LD(pdt + c2 * 8 + tc);
            const float dlt = sigm(s + db_l);
            const float utp = ut_l[ch][tc];
            const float ugp = rintf(utp);
            const float utn = ugp * dlt + (1.f - ugp) * (utp + fminf(dlt, 1.f - utp));
            ut_l[ch][tc] = utn;
            ug_l[ch][tc] = rintf(utn);
        }

        // ---- P1b: GEMM zh = hb(t-1) @ Wr via readlane broadcast ----
        {
            float acc[8];
            #pragma unroll
            for (int r = 0; r < 8; ++r) acc[r] = 0.f;
            #pragma unroll
            for (int kk = 0; kk < 64; ++kk) {
                const float w = w_reg[kk];
                #pragma unroll
                for (int r = 0; r < 8; ++r) {
                    const float hv = bcast_lane(h_reg[kk >> 3], ((kk & 7) << 3) | r);
                    acc[r] += hv * w;
                }
            }
            #pragma unroll
            for (int r = 0; r < 8; ++r) parts[ch][ksI][cI][r] = acc[r];
        }

        // ---- ChainBar#1: parts + ug_l ready (8 wave arrivals, monotonic) ----
        {
            const unsigned tgt = 8u * (unsigned)(t + 1);
            if (cI == 0)
                __hip_atomic_fetch_add(&cbar1[ch], 1u, __ATOMIC_RELEASE,
                                       __HIP_MEMORY_SCOPE_WORKGROUP);
            while (__hip_atomic_load(&cbar1[ch], __ATOMIC_ACQUIRE,
                                     __HIP_MEMORY_SCOPE_WORKGROUP) < tgt)
                __builtin_amdgcn_s_sleep(1);
        }

        // ---- P2: gates (chain waves 0,1) ----
        if (tc < 128) {
            float z[4];
            #pragma unroll
            for (int gg = 0; gg < 4; ++gg) {
                float s = zpre[gg];
                const int c = gg * 16 + guu;
                #pragma unroll
                for (int ks = 0; ks < 8; ++ks) s += parts[ch][ks][c][gr];
                z[gg] = s;
            }
            const float ug = ug_l[ch][gr];
            const float si = sigm(z[0]);
            const float sf = sigm(z[1]);
            const float gt = tanhf(z[2]);
            const float so = sigm(z[3]);
            const float c_n = sf * c_st + si * gt;
            const float h_n = so * tanhf(c_n);
            const float hbv = ug * h_st + (1.f - ug) * h_n;
            const float cbv = ug * c_st + (1.f - ug) * c_n;
            const int b = g * 8 + gr;
            out[(size_t)b * (T_ * U_) + (size_t)t * U_ + u0 + guu] = h_n;
            AGENT_ST(hbg + (t & 1) * 4096 + (size_t)(u0 + guu) * 8 + gr, hbv);
            c_st = cbv; h_st = hbv;
            pdl[ch][guu][gr] = hbv * dk1_l[ch][guu] + cbv * dk2_l[ch][guu];
            // wave1 lane0: release-arrive (orders this wave's hb stores)
            if (t < T_ - 1 && tc == 64)
                __hip_atomic_fetch_add(gctr, 1u, __ATOMIC_RELEASE,
                                       __HIP_MEMORY_SCOPE_AGENT);
        }

        // ---- ChainBar#2: gates done (pdl ready; parts consumption finished) ----
        {
            const unsigned tgt = 8u * (unsigned)(t + 1);
            if (cI == 0)
                __hip_atomic_fetch_add(&cbar2[ch], 1u, __ATOMIC_RELEASE,
                                       __HIP_MEMORY_SCOPE_WORKGROUP);
            while (__hip_atomic_load(&cbar2[ch], __ATOMIC_ACQUIRE,
                                     __HIP_MEMORY_SCOPE_WORKGROUP) < tgt)
                __builtin_amdgcn_s_sleep(1);
        }

        if (t == T_ - 1) break;

        // ---- P2b: chain wave0 lanes 0-7: pd reduce + store; lane0 release-arrive ----
        if (tc < 8) {
            float s = pdl[ch][0][tc];
            #pragma unroll
            for (int j = 1; j < 16; ++j) s += pdl[ch][j][tc];
            AGENT_ST(pdg + (t & 1) * 256 + cu * 8 + tc, s);
        }
        if (tc == 0)
            __hip_atomic_fetch_add(gctr, 1u, __ATOMIC_RELEASE,
                                   __HIP_MEMORY_SCOPE_AGENT);

        // ---- group poll (1 lane/chain) -> LDS go flag ----
        if (tc == 128) {
            const unsigned tgt = 64u * (unsigned)(t + 1);   // 2 arrivals x 32 chains
            while (AGENT_LDA(gctr) < tgt) __builtin_amdgcn_s_sleep(1);
            __hip_atomic_store(&go_l[ch], (unsigned)(t + 1), __ATOMIC_RELEASE,
                               __HIP_MEMORY_SCOPE_WORKGROUP);
        }
        while (__hip_atomic_load(&go_l[ch], __ATOMIC_ACQUIRE,
                                 __HIP_MEMORY_SCOPE_WORKGROUP) < (unsigned)(t + 1))
            __builtin_amdgcn_s_sleep(1);
    }
}

// ---------------- R2 fallback (ws too small): proven 55 ms path --------------------
__global__ __launch_bounds__(NTHR, 4) void skiplstm_kernel_T(
    const float* __restrict__ xT, const float* __restrict__ wk,
    const float* __restrict__ wr, const float* __restrict__ bias,
    const float* __restrict__ dk, const float* __restrict__ dbp,
    float* __restrict__ out, float* __restrict__ hbuf, float* __restrict__ pd)
{
    __shared__ __align__(16) float Wlds[8][1024];
    __shared__ float parts[8][128][9];
    __shared__ float c_state[128][2];
    __shared__ float ut_lds[128];
    __shared__ float bias_l[8];
    __shared__ float dk_l[4];
    __shared__ float db_l;

    const int tid = threadIdx.x;
    const int u0 = blockIdx.x * 2;

    #pragma unroll
    for (int c = 0; c < 8; ++c) {
        const int g = c >> 1, j = c & 1;
        const int gcol = g * U_ + u0 + j;
        Wlds[c][tid] = (tid < D_) ? wk[(size_t)tid * G4 + gcol]
                                  : wr[(size_t)(tid - D_) * G4 + gcol];
    }
    if (tid < 8)  bias_l[tid] = bias[(tid >> 1) * U_ + u0 + (tid & 1)];
    if (tid < 2) { dk_l[tid] = dk[u0 + tid]; dk_l[2 + tid] = dk[U_ + u0 + tid]; }
    if (tid == 0) db_l = dbp[0];
    if (tid < 128) { ut_lds[tid] = 1.0f; c_state[tid][0] = 0.0f; c_state[tid][1] = 0.0f; }
    if (tid < 512) hbuf[blockIdx.x * 512 + tid] = 0.0f;

    cg::grid_group grid = cg::this_grid();
    __syncthreads();
    grid.sync();

    const int b    = tid & 127;
    const int ksub = tid >> 7;

    #pragma unroll 1
    for (int t = 0; t < T_; ++t) {
        const float* __restrict__ hcurT = hbuf + (t & 1) * (U_ * B_);
        float* __restrict__ hnxtT = hbuf + ((t + 1) & 1) * (U_ * B_);

        const float* __restrict__ src = (ksub < 4)
            ? (xT + ((size_t)t * D_ + ksub * 128) * B_ + b)
            : (hcurT + (size_t)(ksub - 4) * 128 * B_ + b);

        float acc[8] = {0.f,0.f,0.f,0.f,0.f,0.f,0.f,0.f};
        #pragma unroll 2
        for (int kq = 0; kq < 32; ++kq) {
            const float v0 = src[(kq * 4 + 0) * B_];
            const float v1 = src[(kq * 4 + 1) * B_];
            const float v2 = src[(kq * 4 + 2) * B_];
            const float v3 = src[(kq * 4 + 3) * B_];
            const int k4 = ksub * 32 + kq;
            #pragma unroll
            for (int c = 0; c < 8; ++c) {
                const float4 w = ((const float4*)(&Wlds[c][0]))[k4];
                acc[c] += v0 * w.x + v1 * w.y + v2 * w.z + v3 * w.w;
            }
        }
        #pragma unroll
        for (int c = 0; c < 8; ++c) parts[ksub][b][c] = acc[c];
        __syncthreads();

        if (tid < 256) {
            const int bb = tid >> 1, j = tid & 1;
            float z[4];
            #pragma unroll
            for (int g = 0; g < 4; ++g) {
                float s = bias_l[g*2 + j];
                #pragma unroll
                for (int ks = 0; ks < 8; ++ks) s += parts[ks][bb][g*2 + j];
                z[g] = s;
            }
            const float ut    = ut_lds[bb];
            const float ug    = rintf(ut);
            const float c_old = c_state[bb][j];
            const float si = sigm(z[0]);
            const float sf = sigm(z[1]);
            const float gg = tanhf(z[2]);
            const float so = sigm(z[3]);
            const float c_n = sf * c_old + si * gg;
            const float h_n = so * tanhf(c_n);
            const float h_old = hcurT[(u0 + j) * B_ + bb];
            const float hbv = ug * h_old + (1.f - ug) * h_n;
            const float cbv = ug * c_old + (1.f - ug) * c_n;
            out[(size_t)bb * (T_ * U_) + (size_t)t * U_ + u0 + j] = h_n;
            hnxtT[(u0 + j) * B_ + bb] = hbv;
            c_state[bb][j] = cbv;
            float p = hbv * dk_l[j] + cbv * dk_l[2 + j];
            p += __shfl_xor(p, 1);
            if (j == 0) pd[(t & 1) * (NBLK * B_) + blockIdx.x * B_ + bb] = p;
        }

        grid.sync();

        {
            const int bb2 = tid >> 3, o = tid & 7;
            const float* __restrict__ pdt = pd + (t & 1) * (NBLK * B_);
            float s = 0.f;
            #pragma unroll 1
            for (int i = 0; i < 32; ++i) s += pdt[(o * 32 + i) * B_ + bb2];
            s += __shfl_xor(s, 1);
            s += __shfl_xor(s, 2);
            s += __shfl_xor(s, 4);
            if (o == 0) {
                const float delta = sigm(s + db_l);
                const float ut = ut_lds[bb2];
                const float ug = rintf(ut);
                ut_lds[bb2] = ug * delta + (1.f - ug) * (ut + fminf(delta, 1.f - ut));
            }
        }
        __syncthreads();
    }
}

// ---------------- host -------------------------------------------------------------
extern "C" void kernel_launch(void* const* d_in, const int* in_sizes, int n_in,
                              void* d_out, int out_size, void* d_ws, size_t ws_size,
                              hipStream_t stream)
{
    (void)in_sizes; (void)n_in; (void)out_size;
    const float* x  = (const float*)d_in[0];
    const float* wk = (const float*)d_in[1];
    const float* wr = (const float*)d_in[2];
    const float* bs = (const float*)d_in[3];
    const float* dk = (const float*)d_in[4];
    const float* db = (const float*)d_in[5];
    float* out = (float*)d_out;

    const size_t xT_b   = (size_t)T_ * D_ * B_ * 4;          // 256 MiB
    const size_t wpk_b  = (size_t)NBLK * 1024 * 8 * 4;       // 8 MiB
    const size_t wp3_b  = (size_t)32 * 512 * 64 * 4;         // 4 MiB
    const size_t hb_b   = (size_t)16 * 2 * 512 * 8 * 4;      // 512 KiB
    const size_t pd_b   = (size_t)16 * 2 * 256 * 4;          // 64 KiB
    const size_t ctrl_b = 4096;
    const size_t zx32_b = (size_t)T_ * G4 * B_ * 4;          // 1 GiB
    const size_t zx16_b = zx32_b / 2;                        // 512 MiB
    const size_t tail_b = hb_b + pd_b + ctrl_b;

    const size_t need_A = zx32_b + xT_b + wpk_b + wp3_b + tail_b;
    const size_t need_B = zx16_b + xT_b + wpk_b + wp3_b + tail_b;

    char* w = (char*)d_ws;

    if (ws_size >= need_B) {
        const bool f32zx = (ws_size >= need_A);
        const size_t zx_b = f32zx ? zx32_b : zx16_b;
        char*  zxp  = w;
        float* xT   = (float*)(w + zx_b);
        float* Wpk  = (float*)(w + zx_b + xT_b);
        float* Wp3  = (float*)(w + zx_b + xT_b + wpk_b);
        float* hb   = (float*)(w + zx_b + xT_b + wpk_b + wp3_b);
        float* pd   = (float*)(w + zx_b + xT_b + wpk_b + wp3_b + hb_b);
        unsigned* ctrl = (unsigned*)(w + zx_b + xT_b + wpk_b + wp3_b + hb_b + pd_b);

        hipMemsetAsync(hb, 0, tail_b, stream);
        transpose_x<<<dim3(T_ * 16 * 4), dim3(256), 0, stream>>>(x, xT);
        pack_w<<<dim3(2048), dim3(1024), 0, stream>>>(wk, wr, Wpk);
        pack_w3<<<dim3(1024), dim3(1024), 0, stream>>>(wr, Wp3);

        if (f32zx) {
            float* zx = (float*)zxp;
            zx_gemm<float><<<dim3(NBLK), dim3(NTHR), 0, stream>>>(xT, Wpk, bs, zx);
            void* args[] = { (void*)&zx, (void*)&Wp3, (void*)&dk, (void*)&db,
                             (void*)&out, (void*)&hb, (void*)&pd, (void*)&ctrl };
            hipLaunchCooperativeKernel(reinterpret_cast<void*>(skiplstm_loop7<float>),
                                       dim3(NBLK), dim3(NTHR), args, 0, stream);
        } else {
            __half* zx = (__half*)zxp;
            zx_gemm<__half><<<dim3(NBLK), dim3(NTHR), 0, stream>>>(xT, Wpk, bs, zx);
            void* args[] = { (void*)&zx, (void*)&Wp3, (void*)&dk, (void*)&db,
                             (void*)&out, (void*)&hb, (void*)&pd, (void*)&ctrl };
            hipLaunchCooperativeKernel(reinterpret_cast<void*>(skiplstm_loop7<__half>),
                                       dim3(NBLK), dim3(NTHR), args, 0, stream);
        }
    } else {
        float* xT   = (float*)d_ws;
        float* hbuf = xT + (size_t)T_ * D_ * B_;
        float* pd   = hbuf + 2 * U_ * B_;
        transpose_x<<<dim3(T_ * 16 * 4), dim3(256), 0, stream>>>(x, xT);
        void* args[] = { (void*)&xT, (void*)&wk, (void*)&wr, (void*)&bs, (void*)&dk, (void*)&db,
                         (void*)&out, (void*)&hbuf, (void*)&pd };
        hipLaunchCooperativeKernel(reinterpret_cast<void*>(skiplstm_kernel_T),
                                   dim3(NBLK), dim3(NTHR), args, 0, stream);
    }
}